// Round 11
// baseline (4303.279 us; speedup 1.0000x reference)
//
#include <hip/hip_runtime.h>
#include <math.h>

// CollapseEngine R11: R9 numerics exactly (pure RNE bf16 MFMA, phi-layout),
// but W A-frags are read DIRECTLY from global (L2-resident 256 KB ws) via
// global_load_dwordx4 -- no LDS staging, no barriers, no vmcnt choreography
// in the layer loop. Waves run fully independent; compiler pipelines freely.
// R10 lesson: ~128 arch-VGPR is the practical budget (doubling state spills).
// phi(ks,G,i) = 32*ks + 16*(i>>2) + 4*G + (i&3),  G = lane>>4.

#define DIMX 256
#define NL 6
#define CPAD 68   // padded float stride for per-G const arrays

typedef float f32x4 __attribute__((ext_vector_type(4)));
typedef short short8 __attribute__((ext_vector_type(8)));
typedef unsigned int u32x4 __attribute__((ext_vector_type(4)));

// RNE-pack f32 pair -> u32 of 2 bf16 (lo = X0, hi = X1)
#define PACKB(X0, X1, DST)                                                       \
    asm("v_cvt_pk_bf16_f32 %0, %1, %2" : "=v"(DST) : "v"(X0), "v"(X1));

// ---------------- W RNE-bf16 frag precompute (phi-ordered, = R9) ----------------
// granule gi = [g(2)][pass(2)][kk(4)][ks2(2)][t8(8)][lane(64)] = 16384 x 16B
// flattened read index: g*8192 + pass*4096 + ks*512 + t8*64 + lane
__global__ void wsplit(const float* __restrict__ W1, const float* __restrict__ W2,
                       u32x4* __restrict__ ws) {
    int gi   = blockIdx.x * 256 + threadIdx.x;      // 0..16383
    int ln   = gi & 63;
    int t8   = (gi >> 6) & 7;
    int ks2  = (gi >> 9) & 1;
    int kk   = (gi >> 10) & 3;
    int pass = (gi >> 12) & 1;
    int g    = (gi >> 13) & 1;
    int ks   = kk * 2 + ks2;
    int m    = (pass * 8 + t8) * 16 + (ln & 15);
    int G    = ln >> 4;
    const float* Wg = g ? W2 : W1;
    unsigned o[4];
#pragma unroll
    for (int p = 0; p < 4; ++p) {
        int f = 32 * ks + ((p >> 1) << 4) + 4 * G + ((p & 1) << 1);
        float x0 = Wg[m * DIMX + f];
        float x1 = Wg[m * DIMX + f + 1];
        unsigned hp;
        PACKB(x0, x1, hp);
        o[p] = hp;
    }
    u32x4 out = {o[0], o[1], o[2], o[3]};
    ws[gi] = out;
}

// ---------------- main fused kernel ----------------

__global__ __launch_bounds__(512, 2)
void collapse_mfma16(const float* __restrict__ h0,
                     const float* __restrict__ b1f,
                     const float* __restrict__ b2f,
                     const float* __restrict__ anchors,
                     const u32x4* __restrict__ ws,
                     float* __restrict__ out_h,
                     float* __restrict__ out_align,
                     float* __restrict__ out_div,
                     float* __restrict__ out_tens,
                     int B)
{
    __shared__ __align__(16) float an_reg[3][272];   // padded (stride CPAD=68)
    __shared__ __align__(16) float b1_reg[272];
    __shared__ __align__(16) float b2_reg[272];
    __shared__ float an_inv[3];

    const int tid  = threadIdx.x;
    const int w    = tid >> 6;
    const int lane = tid & 63;
    const int G    = lane >> 4;          // k-octet / D-row group
    const int c    = lane & 15;          // batch col within wave tile
    const int bglob = blockIdx.x * 128 + w * 16 + c;

    // anchor inverse norms (waves 0..2)
    if (w < 3) {
        const float4 av = *(const float4*)&anchors[w * DIMX + lane * 4];
        float ss = av.x * av.x + av.y * av.y + av.z * av.z + av.w * av.w;
#pragma unroll
        for (int m = 1; m < 64; m <<= 1) ss += __shfl_xor(ss, m, 64);
        if (lane == 0) an_inv[w] = 1.0f / fmaxf(sqrtf(ss), 1e-12f);
    }
    __syncthreads();

    // const arrays in phi-layout, padded: idx = Gc*CPAD + s,
    // feat f = 16*(s>>2) + 4*Gc + (s&3)
    {
        int idx = tid & 255;
        int Gc = idx >> 6, s = idx & 63;
        int f = 16 * (s >> 2) + 4 * Gc + (s & 3);
        int pidx = Gc * CPAD + s;
        if (tid < 256) {
            b1_reg[pidx] = b1f[f];
            b2_reg[pidx] = b2f[f];
        } else {
#pragma unroll
            for (int k = 0; k < 3; ++k)
                an_reg[k][pidx] = anchors[k * DIMX + f] * an_inv[k];
        }
    }
    __syncthreads();

    // load h0 into phi-layout regs: hr[mt*4+r] = h0[row][16mt+4G+r]
    float hr[64];
#pragma unroll
    for (int mt = 0; mt < 16; ++mt) {
        const float4 v = *(const float4*)&h0[(size_t)bglob * DIMX + 16 * mt + 4 * G];
        hr[mt * 4 + 0] = v.x; hr[mt * 4 + 1] = v.y;
        hr[mt * 4 + 2] = v.z; hr[mt * 4 + 3] = v.w;
    }

#pragma unroll 1
    for (int layer = 0; layer < NL; ++layer) {
        // ---------- stats: p0=|h|^2, dk=h.Ak ; |h-Ak|^2 = p0-2dk+1 ----------
        float p0 = 0, d0 = 0, d1 = 0, d2 = 0;
#pragma unroll
        for (int q = 0; q < 16; ++q) {
            const float4 a0 = *(const float4*)&an_reg[0][G * CPAD + q * 4];
            const float4 a1 = *(const float4*)&an_reg[1][G * CPAD + q * 4];
            const float4 a2 = *(const float4*)&an_reg[2][G * CPAD + q * 4];
            float x;
            x = hr[q*4+0]; p0 += x*x; d0 += x*a0.x; d1 += x*a1.x; d2 += x*a2.x;
            x = hr[q*4+1]; p0 += x*x; d0 += x*a0.y; d1 += x*a1.y; d2 += x*a2.y;
            x = hr[q*4+2]; p0 += x*x; d0 += x*a0.z; d1 += x*a1.z; d2 += x*a2.z;
            x = hr[q*4+3]; p0 += x*x; d0 += x*a0.w; d1 += x*a1.w; d2 += x*a2.w;
        }
        p0 += __shfl_xor(p0, 16); d0 += __shfl_xor(d0, 16);
        d1 += __shfl_xor(d1, 16); d2 += __shfl_xor(d2, 16);
        p0 += __shfl_xor(p0, 32); d0 += __shfl_xor(d0, 32);
        d1 += __shfl_xor(d1, 32); d2 += __shfl_xor(d2, 32);
        const float inv_rn = 1.0f / fmaxf(sqrtf(p0), 1e-12f);
        const float al0 = d0 * inv_rn, al1 = d1 * inv_rn, al2 = d2 * inv_rn;
        const float dv0 = 1.0f - al0, dv1 = 1.0f - al1, dv2 = 1.0f - al2;
        const float c0 = -0.10f * dv0 / fmaxf(sqrtf(fmaxf(p0 - 2.0f*d0 + 1.0f, 0.0f)), 1e-12f);
        const float c1 = -0.10f * dv1 / fmaxf(sqrtf(fmaxf(p0 - 2.0f*d1 + 1.0f, 0.0f)), 1e-12f);
        const float c2 = -0.05f * dv2 / fmaxf(sqrtf(fmaxf(p0 - 2.0f*d2 + 1.0f, 0.0f)), 1e-12f);
        if (G == 0) {
            const long long tb = ((long long)layer * B + bglob) * 3;
            out_align[tb+0] = al0; out_align[tb+1] = al1; out_align[tb+2] = al2;
            out_div[tb+0] = dv0;   out_div[tb+1] = dv1;   out_div[tb+2] = dv2;
            out_tens[tb+0] = dv0*dv0; out_tens[tb+1] = dv1*dv1; out_tens[tb+2] = dv2*dv2;
        }

        // ---------- G1: t = tanh(W1 h + b1) ----------
        unsigned tph[32];
#pragma unroll
        for (int pass = 0; pass < 2; ++pass) {
            f32x4 ac[8];
#pragma unroll
            for (int j = 0; j < 8; ++j) ac[j] = (f32x4)(0.0f);
#pragma unroll
            for (int ks = 0; ks < 8; ++ks) {
                unsigned bh[4];
#pragma unroll
                for (int p = 0; p < 4; ++p)
                    PACKB(hr[8*ks + 2*p], hr[8*ks + 2*p + 1], bh[p]);
                u32x4 thi = {bh[0], bh[1], bh[2], bh[3]};
                const short8 Bh = __builtin_bit_cast(short8, thi);
                const u32x4* wp = ws + pass*4096 + ks*512 + lane;
#pragma unroll
                for (int j = 0; j < 8; ++j) {
                    const short8 Ah = __builtin_bit_cast(short8, wp[j*64]);
                    ac[j] = __builtin_amdgcn_mfma_f32_16x16x32_bf16(Ah, Bh, ac[j], 0, 0, 0);
                }
            }
            // tanh + b1, pack into t (phi-layout)
#pragma unroll
            for (int j = 0; j < 8; ++j) {
                const int mt = pass * 8 + j;
                const float4 bq = *(const float4*)&b1_reg[G * CPAD + mt * 4];
                float tv[4];
#pragma unroll
                for (int r = 0; r < 4; ++r) {
                    float x = ac[j][r] + ((r==0)?bq.x:(r==1)?bq.y:(r==2)?bq.z:bq.w);
                    float e = __expf(2.0f * x);
                    tv[r] = 1.0f - 2.0f * __builtin_amdgcn_rcpf(e + 1.0f);
                }
                const int ti = 4 * (mt >> 1) + 2 * (mt & 1);
                PACKB(tv[0], tv[1], tph[ti]);
                PACKB(tv[2], tv[3], tph[ti + 1]);
            }
        }

        // ---------- G2: h' = (h + b2 + force) + W2 t ----------
        const float csum = 1.0f + c0 + c1 + c2;
#pragma unroll
        for (int pass = 0; pass < 2; ++pass) {
            f32x4 ac[8];
#pragma unroll
            for (int j = 0; j < 8; ++j) {
                const int mt = pass * 8 + j;
                const float4 a0 = *(const float4*)&an_reg[0][G * CPAD + mt * 4];
                const float4 a1 = *(const float4*)&an_reg[1][G * CPAD + mt * 4];
                const float4 a2 = *(const float4*)&an_reg[2][G * CPAD + mt * 4];
                const float4 bq = *(const float4*)&b2_reg[G * CPAD + mt * 4];
                ac[j][0] = hr[mt*4+0]*csum - (c0*a0.x + c1*a1.x + c2*a2.x) + bq.x;
                ac[j][1] = hr[mt*4+1]*csum - (c0*a0.y + c1*a1.y + c2*a2.y) + bq.y;
                ac[j][2] = hr[mt*4+2]*csum - (c0*a0.z + c1*a1.z + c2*a2.z) + bq.z;
                ac[j][3] = hr[mt*4+3]*csum - (c0*a0.w + c1*a1.w + c2*a2.w) + bq.w;
            }
#pragma unroll
            for (int ks = 0; ks < 8; ++ks) {
                u32x4 thi = {tph[4*ks+0], tph[4*ks+1], tph[4*ks+2], tph[4*ks+3]};
                const short8 Bh = __builtin_bit_cast(short8, thi);
                const u32x4* wp = ws + 8192 + pass*4096 + ks*512 + lane;
#pragma unroll
                for (int j = 0; j < 8; ++j) {
                    const short8 Ah = __builtin_bit_cast(short8, wp[j*64]);
                    ac[j] = __builtin_amdgcn_mfma_f32_16x16x32_bf16(Ah, Bh, ac[j], 0, 0, 0);
                }
            }
#pragma unroll
            for (int j = 0; j < 8; ++j) {
                const int mt = pass * 8 + j;
                hr[mt*4+0] = ac[j][0]; hr[mt*4+1] = ac[j][1];
                hr[mt*4+2] = ac[j][2]; hr[mt*4+3] = ac[j][3];
            }
        }

        // ---------- norm clip (in regs) ----------
        {
            float ss = 0.0f;
#pragma unroll
            for (int s = 0; s < 64; ++s) ss += hr[s] * hr[s];
            ss += __shfl_xor(ss, 16);
            ss += __shfl_xor(ss, 32);
            const float n = sqrtf(ss);
            const float sc = (n > 10.0f) ? (10.0f / (n + 1e-8f)) : 1.0f;
#pragma unroll
            for (int s = 0; s < 64; ++s) hr[s] *= sc;
        }
    }

    // ---------- store h_final ----------
#pragma unroll
    for (int mt = 0; mt < 16; ++mt) {
        float4 v;
        v.x = hr[mt*4+0]; v.y = hr[mt*4+1]; v.z = hr[mt*4+2]; v.w = hr[mt*4+3];
        *(float4*)&out_h[(size_t)bglob * DIMX + 16 * mt + 4 * G] = v;
    }
}

extern "C" void kernel_launch(void* const* d_in, const int* in_sizes, int n_in,
                              void* d_out, int out_size, void* d_ws, size_t ws_size,
                              hipStream_t stream) {
    const float* h0      = (const float*)d_in[0];
    const float* W1      = (const float*)d_in[1];
    const float* b1      = (const float*)d_in[2];
    const float* W2      = (const float*)d_in[3];
    const float* b2      = (const float*)d_in[4];
    const float* anchors = (const float*)d_in[5];
    const int B = in_sizes[0] / DIMX;

    float* out_h     = (float*)d_out;
    float* out_align = out_h + (long long)B * DIMX;
    float* out_div   = out_align + (long long)NL * B * 3;
    float* out_tens  = out_div   + (long long)NL * B * 3;

    u32x4* ws = (u32x4*)d_ws;   // 256 KiB

    hipLaunchKernelGGL(wsplit, dim3(64), dim3(256), 0, stream, W1, W2, ws);
    hipLaunchKernelGGL(collapse_mfma16, dim3(B / 128), dim3(512), 0, stream,
                       h0, b1, b2, anchors, ws,
                       out_h, out_align, out_div, out_tens, B);
}

// Round 12
// 985.858 us; speedup vs baseline: 4.3650x; 4.3650x over previous
//
#include <hip/hip_runtime.h>
#include <math.h>

// CollapseEngine R12: R9 numerics exactly (pure RNE bf16 MFMA, phi-layout),
// restructured staging: TWO 64KB pass-buffers in LDS (1 block/CU), 4 barriers
// per layer (vs R9's 16 windows). Each pass: syncthreads (free drain - loads
// issued a full pass ago) -> issue next pass's stage -> 64 ds_read + 64 MFMA
// with no internal barriers. Waves drift freely within a pass.
// R10/R11 lessons: 128-VGPR budget; W must be LDS-staged (direct L2 reads
// miss to HBM and starve MFMA).
// phi(ks,G,i) = 32*ks + 16*(i>>2) + 4*G + (i&3),  G = lane>>4.

#define DIMX 256
#define NL 6
#define CPAD 68   // padded float stride for per-G const arrays

typedef float f32x4 __attribute__((ext_vector_type(4)));
typedef short short8 __attribute__((ext_vector_type(8)));
typedef unsigned int u32x4 __attribute__((ext_vector_type(4)));

// RNE-pack f32 pair -> u32 of 2 bf16 (lo = X0, hi = X1)
#define PACKB(X0, X1, DST)                                                       \
    asm("v_cvt_pk_bf16_f32 %0, %1, %2" : "=v"(DST) : "v"(X0), "v"(X1));

// ---------------- W RNE-bf16 frag precompute (phi-ordered, = R9/R11) -----------
// flattened index: g*8192 + pass*4096 + ks*512 + t8*64 + lane   (16B granules)
__global__ void wsplit(const float* __restrict__ W1, const float* __restrict__ W2,
                       u32x4* __restrict__ ws) {
    int gi   = blockIdx.x * 256 + threadIdx.x;      // 0..16383
    int ln   = gi & 63;
    int t8   = (gi >> 6) & 7;
    int ks2  = (gi >> 9) & 1;
    int kk   = (gi >> 10) & 3;
    int pass = (gi >> 12) & 1;
    int g    = (gi >> 13) & 1;
    int ks   = kk * 2 + ks2;
    int m    = (pass * 8 + t8) * 16 + (ln & 15);
    int G    = ln >> 4;
    const float* Wg = g ? W2 : W1;
    unsigned o[4];
#pragma unroll
    for (int p = 0; p < 4; ++p) {
        int f = 32 * ks + ((p >> 1) << 4) + 4 * G + ((p & 1) << 1);
        float x0 = Wg[m * DIMX + f];
        float x1 = Wg[m * DIMX + f + 1];
        unsigned hp;
        PACKB(x0, x1, hp);
        o[p] = hp;
    }
    u32x4 out = {o[0], o[1], o[2], o[3]};
    ws[gi] = out;
}

// ---------------- main fused kernel ----------------

// stage one 64KB pass-chunk (4096 granules): 8 waves x 8 x (16B x 64 lanes)
#define STAGEP(gChunkBase, ldsBase)                                              \
    {                                                                            \
        _Pragma("unroll")                                                        \
        for (int i_ = 0; i_ < 8; ++i_) {                                         \
            const int off_ = w * 512 + i_ * 64;                                  \
            __builtin_amdgcn_global_load_lds(                                    \
                (const __attribute__((address_space(1))) void*)(ws + (gChunkBase) + off_ + lane), \
                (__attribute__((address_space(3))) void*)(&wf[(ldsBase) + off_]),               \
                16, 0, 0);                                                       \
        }                                                                        \
    }

__global__ __launch_bounds__(512, 1)
void collapse_mfma16(const float* __restrict__ h0,
                     const float* __restrict__ b1f,
                     const float* __restrict__ b2f,
                     const float* __restrict__ anchors,
                     const u32x4* __restrict__ ws,
                     float* __restrict__ out_h,
                     float* __restrict__ out_align,
                     float* __restrict__ out_div,
                     float* __restrict__ out_tens,
                     int B)
{
    __shared__ __align__(16) u32x4 wf[8192];         // 2 x 64KB pass buffers
    __shared__ __align__(16) float an_reg[3][272];   // padded (stride CPAD=68)
    __shared__ __align__(16) float b1_reg[272];
    __shared__ __align__(16) float b2_reg[272];
    __shared__ float an_inv[3];

    const int tid  = threadIdx.x;
    const int w    = tid >> 6;
    const int lane = tid & 63;
    const int G    = lane >> 4;          // k-octet / D-row group
    const int c    = lane & 15;          // batch col within wave tile
    const int bglob = blockIdx.x * 128 + w * 16 + c;

    // anchor inverse norms (waves 0..2)
    if (w < 3) {
        const float4 av = *(const float4*)&anchors[w * DIMX + lane * 4];
        float ss = av.x * av.x + av.y * av.y + av.z * av.z + av.w * av.w;
#pragma unroll
        for (int m = 1; m < 64; m <<= 1) ss += __shfl_xor(ss, m, 64);
        if (lane == 0) an_inv[w] = 1.0f / fmaxf(sqrtf(ss), 1e-12f);
    }
    __syncthreads();

    // const arrays in phi-layout, padded: idx = Gc*CPAD + s,
    // feat f = 16*(s>>2) + 4*Gc + (s&3)
    {
        int idx = tid & 255;
        int Gc = idx >> 6, s = idx & 63;
        int f = 16 * (s >> 2) + 4 * Gc + (s & 3);
        int pidx = Gc * CPAD + s;
        if (tid < 256) {
            b1_reg[pidx] = b1f[f];
            b2_reg[pidx] = b2f[f];
        } else {
#pragma unroll
            for (int k = 0; k < 3; ++k)
                an_reg[k][pidx] = anchors[k * DIMX + f] * an_inv[k];
        }
    }

    // load h0 into phi-layout regs: hr[mt*4+r] = h0[row][16mt+4G+r]
    float hr[64];
#pragma unroll
    for (int mt = 0; mt < 16; ++mt) {
        const float4 v = *(const float4*)&h0[(size_t)bglob * DIMX + 16 * mt + 4 * G];
        hr[mt * 4 + 0] = v.x; hr[mt * 4 + 1] = v.y;
        hr[mt * 4 + 2] = v.z; hr[mt * 4 + 3] = v.w;
    }

    // prologue: stage pass-chunk 0 (G1,p0) into buf0
    STAGEP(0, 0);

#pragma unroll 1
    for (int layer = 0; layer < NL; ++layer) {
        // ---------- stats: p0=|h|^2, dk=h.Ak ; |h-Ak|^2 = p0-2dk+1 ----------
        float p0 = 0, d0 = 0, d1 = 0, d2 = 0;
#pragma unroll
        for (int q = 0; q < 16; ++q) {
            const float4 a0 = *(const float4*)&an_reg[0][G * CPAD + q * 4];
            const float4 a1 = *(const float4*)&an_reg[1][G * CPAD + q * 4];
            const float4 a2 = *(const float4*)&an_reg[2][G * CPAD + q * 4];
            float x;
            x = hr[q*4+0]; p0 += x*x; d0 += x*a0.x; d1 += x*a1.x; d2 += x*a2.x;
            x = hr[q*4+1]; p0 += x*x; d0 += x*a0.y; d1 += x*a1.y; d2 += x*a2.y;
            x = hr[q*4+2]; p0 += x*x; d0 += x*a0.z; d1 += x*a1.z; d2 += x*a2.z;
            x = hr[q*4+3]; p0 += x*x; d0 += x*a0.w; d1 += x*a1.w; d2 += x*a2.w;
        }
        p0 += __shfl_xor(p0, 16); d0 += __shfl_xor(d0, 16);
        d1 += __shfl_xor(d1, 16); d2 += __shfl_xor(d2, 16);
        p0 += __shfl_xor(p0, 32); d0 += __shfl_xor(d0, 32);
        d1 += __shfl_xor(d1, 32); d2 += __shfl_xor(d2, 32);
        const float inv_rn = 1.0f / fmaxf(sqrtf(p0), 1e-12f);
        const float al0 = d0 * inv_rn, al1 = d1 * inv_rn, al2 = d2 * inv_rn;
        const float dv0 = 1.0f - al0, dv1 = 1.0f - al1, dv2 = 1.0f - al2;
        const float c0 = -0.10f * dv0 / fmaxf(sqrtf(fmaxf(p0 - 2.0f*d0 + 1.0f, 0.0f)), 1e-12f);
        const float c1 = -0.10f * dv1 / fmaxf(sqrtf(fmaxf(p0 - 2.0f*d1 + 1.0f, 0.0f)), 1e-12f);
        const float c2 = -0.05f * dv2 / fmaxf(sqrtf(fmaxf(p0 - 2.0f*d2 + 1.0f, 0.0f)), 1e-12f);
        if (G == 0) {
            const long long tb = ((long long)layer * B + bglob) * 3;
            out_align[tb+0] = al0; out_align[tb+1] = al1; out_align[tb+2] = al2;
            out_div[tb+0] = dv0;   out_div[tb+1] = dv1;   out_div[tb+2] = dv2;
            out_tens[tb+0] = dv0*dv0; out_tens[tb+1] = dv1*dv1; out_tens[tb+2] = dv2*dv2;
        }

        // ---------- G1: t = tanh(W1 h + b1); passes q=0,1 ----------
        unsigned tph[32];
#pragma unroll
        for (int pass = 0; pass < 2; ++pass) {
            const int q = pass;                      // global pass idx 0..3
            const int bufB = (q & 1) * 4096;
            __syncthreads();                         // this pass's stage complete
            STAGEP((((q + 1) & 3) * 4096), (((q + 1) & 1) * 4096));  // next pass
            f32x4 ac[8];
#pragma unroll
            for (int j = 0; j < 8; ++j) ac[j] = (f32x4)(0.0f);
#pragma unroll
            for (int ks = 0; ks < 8; ++ks) {
                unsigned bh[4];
#pragma unroll
                for (int p = 0; p < 4; ++p)
                    PACKB(hr[8*ks + 2*p], hr[8*ks + 2*p + 1], bh[p]);
                u32x4 thi = {bh[0], bh[1], bh[2], bh[3]};
                const short8 Bh = __builtin_bit_cast(short8, thi);
#pragma unroll
                for (int j = 0; j < 8; ++j) {
                    const short8 Ah = __builtin_bit_cast(short8,
                        wf[bufB + ks*512 + j*64 + lane]);
                    ac[j] = __builtin_amdgcn_mfma_f32_16x16x32_bf16(Ah, Bh, ac[j], 0, 0, 0);
                }
            }
            // tanh + b1, pack into t (phi-layout)
#pragma unroll
            for (int j = 0; j < 8; ++j) {
                const int mt = pass * 8 + j;
                const float4 bq = *(const float4*)&b1_reg[G * CPAD + mt * 4];
                float tv[4];
#pragma unroll
                for (int r = 0; r < 4; ++r) {
                    float x = ac[j][r] + ((r==0)?bq.x:(r==1)?bq.y:(r==2)?bq.z:bq.w);
                    float e = __expf(2.0f * x);
                    tv[r] = 1.0f - 2.0f * __builtin_amdgcn_rcpf(e + 1.0f);
                }
                const int ti = 4 * (mt >> 1) + 2 * (mt & 1);
                PACKB(tv[0], tv[1], tph[ti]);
                PACKB(tv[2], tv[3], tph[ti + 1]);
            }
        }

        // ---------- G2: h' = (h + b2 + force) + W2 t; passes q=2,3 ----------
        const float csum = 1.0f + c0 + c1 + c2;
#pragma unroll
        for (int pass = 0; pass < 2; ++pass) {
            const int q = 2 + pass;
            const int bufB = (q & 1) * 4096;
            f32x4 ac[8];
#pragma unroll
            for (int j = 0; j < 8; ++j) {
                const int mt = pass * 8 + j;
                const float4 a0 = *(const float4*)&an_reg[0][G * CPAD + mt * 4];
                const float4 a1 = *(const float4*)&an_reg[1][G * CPAD + mt * 4];
                const float4 a2 = *(const float4*)&an_reg[2][G * CPAD + mt * 4];
                const float4 bq = *(const float4*)&b2_reg[G * CPAD + mt * 4];
                ac[j][0] = hr[mt*4+0]*csum - (c0*a0.x + c1*a1.x + c2*a2.x) + bq.x;
                ac[j][1] = hr[mt*4+1]*csum - (c0*a0.y + c1*a1.y + c2*a2.y) + bq.y;
                ac[j][2] = hr[mt*4+2]*csum - (c0*a0.z + c1*a1.z + c2*a2.z) + bq.z;
                ac[j][3] = hr[mt*4+3]*csum - (c0*a0.w + c1*a1.w + c2*a2.w) + bq.w;
            }
            __syncthreads();                         // this pass's stage complete
            STAGEP((((q + 1) & 3) * 4096), (((q + 1) & 1) * 4096));  // next (wraps)
#pragma unroll
            for (int ks = 0; ks < 8; ++ks) {
                u32x4 thi = {tph[4*ks+0], tph[4*ks+1], tph[4*ks+2], tph[4*ks+3]};
                const short8 Bh = __builtin_bit_cast(short8, thi);
#pragma unroll
                for (int j = 0; j < 8; ++j) {
                    const short8 Ah = __builtin_bit_cast(short8,
                        wf[bufB + ks*512 + j*64 + lane]);
                    ac[j] = __builtin_amdgcn_mfma_f32_16x16x32_bf16(Ah, Bh, ac[j], 0, 0, 0);
                }
            }
#pragma unroll
            for (int j = 0; j < 8; ++j) {
                const int mt = pass * 8 + j;
                hr[mt*4+0] = ac[j][0]; hr[mt*4+1] = ac[j][1];
                hr[mt*4+2] = ac[j][2]; hr[mt*4+3] = ac[j][3];
            }
        }

        // ---------- norm clip (in regs) ----------
        {
            float ss = 0.0f;
#pragma unroll
            for (int s = 0; s < 64; ++s) ss += hr[s] * hr[s];
            ss += __shfl_xor(ss, 16);
            ss += __shfl_xor(ss, 32);
            const float n = sqrtf(ss);
            const float sc = (n > 10.0f) ? (10.0f / (n + 1e-8f)) : 1.0f;
#pragma unroll
            for (int s = 0; s < 64; ++s) hr[s] *= sc;
        }
    }

    // ---------- store h_final ----------
#pragma unroll
    for (int mt = 0; mt < 16; ++mt) {
        float4 v;
        v.x = hr[mt*4+0]; v.y = hr[mt*4+1]; v.z = hr[mt*4+2]; v.w = hr[mt*4+3];
        *(float4*)&out_h[(size_t)bglob * DIMX + 16 * mt + 4 * G] = v;
    }
}

extern "C" void kernel_launch(void* const* d_in, const int* in_sizes, int n_in,
                              void* d_out, int out_size, void* d_ws, size_t ws_size,
                              hipStream_t stream) {
    const float* h0      = (const float*)d_in[0];
    const float* W1      = (const float*)d_in[1];
    const float* b1      = (const float*)d_in[2];
    const float* W2      = (const float*)d_in[3];
    const float* b2      = (const float*)d_in[4];
    const float* anchors = (const float*)d_in[5];
    const int B = in_sizes[0] / DIMX;

    float* out_h     = (float*)d_out;
    float* out_align = out_h + (long long)B * DIMX;
    float* out_div   = out_align + (long long)NL * B * 3;
    float* out_tens  = out_div   + (long long)NL * B * 3;

    u32x4* ws = (u32x4*)d_ws;   // 256 KiB

    hipLaunchKernelGGL(wsplit, dim3(64), dim3(256), 0, stream, W1, W2, ws);
    hipLaunchKernelGGL(collapse_mfma16, dim3(B / 128), dim3(512), 0, stream,
                       h0, b1, b2, anchors, ws,
                       out_h, out_align, out_div, out_tens, B);
}

// Round 13
// 809.996 us; speedup vs baseline: 5.3127x; 1.2171x over previous
//
#include <hip/hip_runtime.h>
#include <math.h>

// CollapseEngine R13: R9 kernel body bit-identical (pure RNE bf16 MFMA,
// phi-layout, counted-vmcnt 4x16KB pipeline), but 256-thread blocks (4 waves,
// 64 rows), grid 2048 -> TWO INDEPENDENT blocks per CU (unified VGPR+AGPR
// ~192/wave => 10-wave budget; 2 blocks x 4 waves fits, R9's 8-wave block
// left no room for a second). Independent blocks decouple barrier convoys.
// phi(ks,G,i) = 32*ks + 16*(i>>2) + 4*G + (i&3),  G = lane>>4.

#define DIMX 256
#define NL 6
#define CPAD 68   // padded float stride for per-G const arrays

typedef float f32x4 __attribute__((ext_vector_type(4)));
typedef short short8 __attribute__((ext_vector_type(8)));
typedef unsigned int u32x4 __attribute__((ext_vector_type(4)));

// 16 chunks of 1024 granules (16KB); chunk c = (g*2+pass)*4 + kk, kk=ks>>1
#define CHB(c) ((c) * 1024)

// RNE-pack f32 pair -> u32 of 2 bf16 (lo = X0, hi = X1)
#define PACKB(X0, X1, DST)                                                       \
    asm("v_cvt_pk_bf16_f32 %0, %1, %2" : "=v"(DST) : "v"(X0), "v"(X1));

// ---------------- W RNE-bf16 frag precompute (phi-ordered, = R9) ----------------
__global__ void wsplit(const float* __restrict__ W1, const float* __restrict__ W2,
                       u32x4* __restrict__ ws) {
    int gi   = blockIdx.x * 256 + threadIdx.x;      // 0..16383
    int ln   = gi & 63;
    int t8   = (gi >> 6) & 7;
    int ks2  = (gi >> 9) & 1;
    int kk   = (gi >> 10) & 3;
    int pass = (gi >> 12) & 1;
    int g    = (gi >> 13) & 1;
    int ks   = kk * 2 + ks2;
    int m    = (pass * 8 + t8) * 16 + (ln & 15);
    int G    = ln >> 4;
    const float* Wg = g ? W2 : W1;
    unsigned o[4];
#pragma unroll
    for (int p = 0; p < 4; ++p) {
        int f = 32 * ks + ((p >> 1) << 4) + 4 * G + ((p & 1) << 1);
        float x0 = Wg[m * DIMX + f];
        float x1 = Wg[m * DIMX + f + 1];
        unsigned hp;
        PACKB(x0, x1, hp);
        o[p] = hp;
    }
    u32x4 out = {o[0], o[1], o[2], o[3]};
    ws[gi] = out;
}

// ---------------- main fused kernel ----------------

// stage one 16KB chunk (1024 granules): 256 thr x 4 x 16B
#define STAGE(gIdxBase, ldsSlotBase)                                             \
    {                                                                            \
        _Pragma("unroll")                                                        \
        for (int i_ = 0; i_ < 4; ++i_) {                                         \
            const int off_ = ((w * 4 + i_) << 6);                                \
            __builtin_amdgcn_global_load_lds(                                    \
                (const __attribute__((address_space(1))) void*)(ws + (gIdxBase) + off_ + lane), \
                (__attribute__((address_space(3))) void*)(&wf[(ldsSlotBase) + off_]),           \
                16, 0, 0);                                                       \
        }                                                                        \
    }

// counted-vmcnt pipeline barrier: own chunk's 4 loads complete, the 2
// prefetched chunks (8 loads) stay in flight. Raw barrier, no drain.
#define PIPE_SYNC()                                                              \
    {                                                                            \
        asm volatile("s_waitcnt vmcnt(8)" ::: "memory");                         \
        __builtin_amdgcn_sched_barrier(0);                                       \
        __builtin_amdgcn_s_barrier();                                            \
        __builtin_amdgcn_sched_barrier(0);                                       \
    }

__global__ __launch_bounds__(256, 2)
void collapse_mfma16(const float* __restrict__ h0,
                     const float* __restrict__ b1f,
                     const float* __restrict__ b2f,
                     const float* __restrict__ anchors,
                     const u32x4* __restrict__ ws,
                     float* __restrict__ out_h,
                     float* __restrict__ out_align,
                     float* __restrict__ out_div,
                     float* __restrict__ out_tens,
                     int B)
{
    __shared__ __align__(16) u32x4 wf[4096];         // 4 x 16KB W-frag buffers
    __shared__ __align__(16) float an_reg[3][272];   // padded (stride CPAD=68)
    __shared__ __align__(16) float b1_reg[272];
    __shared__ __align__(16) float b2_reg[272];
    __shared__ float an_inv[3];

    const int tid  = threadIdx.x;
    const int w    = tid >> 6;
    const int lane = tid & 63;
    const int G    = lane >> 4;          // k-octet / D-row group
    const int c    = lane & 15;          // batch col within wave tile
    const int bglob = blockIdx.x * 64 + w * 16 + c;

    // anchor inverse norms (waves 0..2)
    if (w < 3) {
        const float4 av = *(const float4*)&anchors[w * DIMX + lane * 4];
        float ss = av.x * av.x + av.y * av.y + av.z * av.z + av.w * av.w;
#pragma unroll
        for (int m = 1; m < 64; m <<= 1) ss += __shfl_xor(ss, m, 64);
        if (lane == 0) an_inv[w] = 1.0f / fmaxf(sqrtf(ss), 1e-12f);
    }
    __syncthreads();

    // const arrays in phi-layout, padded: idx = Gc*CPAD + s,
    // feat f = 16*(s>>2) + 4*Gc + (s&3)   (256 threads: each writes all arrays)
    {
        int idx = tid;
        int Gc = idx >> 6, s = idx & 63;
        int f = 16 * (s >> 2) + 4 * Gc + (s & 3);
        int pidx = Gc * CPAD + s;
        b1_reg[pidx] = b1f[f];
        b2_reg[pidx] = b2f[f];
#pragma unroll
        for (int k = 0; k < 3; ++k)
            an_reg[k][pidx] = anchors[k * DIMX + f] * an_inv[k];
    }
    __syncthreads();

    // load h0 into phi-layout regs: hr[mt*4+r] = h0[row][16mt+4G+r]
    float hr[64];
#pragma unroll
    for (int mt = 0; mt < 16; ++mt) {
        const float4 v = *(const float4*)&h0[(size_t)bglob * DIMX + 16 * mt + 4 * G];
        hr[mt * 4 + 0] = v.x; hr[mt * 4 + 1] = v.y;
        hr[mt * 4 + 2] = v.z; hr[mt * 4 + 3] = v.w;
    }

    // pipeline prologue: prefetch chunks 0,1,2 into bufs 0,1,2
    STAGE(CHB(0), 0);
    STAGE(CHB(1), 1024);
    STAGE(CHB(2), 2048);

#pragma unroll 1
    for (int layer = 0; layer < NL; ++layer) {
        // ---------- stats: p0=|h|^2, dk=h.Ak ; |h-Ak|^2 = p0-2dk+1 ----------
        float p0 = 0, d0 = 0, d1 = 0, d2 = 0;
#pragma unroll
        for (int q = 0; q < 16; ++q) {
            const float4 a0 = *(const float4*)&an_reg[0][G * CPAD + q * 4];
            const float4 a1 = *(const float4*)&an_reg[1][G * CPAD + q * 4];
            const float4 a2 = *(const float4*)&an_reg[2][G * CPAD + q * 4];
            float x;
            x = hr[q*4+0]; p0 += x*x; d0 += x*a0.x; d1 += x*a1.x; d2 += x*a2.x;
            x = hr[q*4+1]; p0 += x*x; d0 += x*a0.y; d1 += x*a1.y; d2 += x*a2.y;
            x = hr[q*4+2]; p0 += x*x; d0 += x*a0.z; d1 += x*a1.z; d2 += x*a2.z;
            x = hr[q*4+3]; p0 += x*x; d0 += x*a0.w; d1 += x*a1.w; d2 += x*a2.w;
        }
        p0 += __shfl_xor(p0, 16); d0 += __shfl_xor(d0, 16);
        d1 += __shfl_xor(d1, 16); d2 += __shfl_xor(d2, 16);
        p0 += __shfl_xor(p0, 32); d0 += __shfl_xor(d0, 32);
        d1 += __shfl_xor(d1, 32); d2 += __shfl_xor(d2, 32);
        const float inv_rn = 1.0f / fmaxf(sqrtf(p0), 1e-12f);
        const float al0 = d0 * inv_rn, al1 = d1 * inv_rn, al2 = d2 * inv_rn;
        const float dv0 = 1.0f - al0, dv1 = 1.0f - al1, dv2 = 1.0f - al2;
        const float c0 = -0.10f * dv0 / fmaxf(sqrtf(fmaxf(p0 - 2.0f*d0 + 1.0f, 0.0f)), 1e-12f);
        const float c1 = -0.10f * dv1 / fmaxf(sqrtf(fmaxf(p0 - 2.0f*d1 + 1.0f, 0.0f)), 1e-12f);
        const float c2 = -0.05f * dv2 / fmaxf(sqrtf(fmaxf(p0 - 2.0f*d2 + 1.0f, 0.0f)), 1e-12f);
        if (G == 0) {
            const long long tb = ((long long)layer * B + bglob) * 3;
            out_align[tb+0] = al0; out_align[tb+1] = al1; out_align[tb+2] = al2;
            out_div[tb+0] = dv0;   out_div[tb+1] = dv1;   out_div[tb+2] = dv2;
            out_tens[tb+0] = dv0*dv0; out_tens[tb+1] = dv1*dv1; out_tens[tb+2] = dv2*dv2;
        }

        // ---------- G1: t = tanh(W1 h + b1); windows = (pass, kk) ----------
        unsigned tph[32];
#pragma unroll
        for (int pass = 0; pass < 2; ++pass) {
            f32x4 ac[8];
#pragma unroll
            for (int j = 0; j < 8; ++j) ac[j] = (f32x4)(0.0f);
#pragma unroll
            for (int kk = 0; kk < 4; ++kk) {
                const int s = pass * 4 + kk;
                PIPE_SYNC();
                STAGE(CHB((s + 3) & 15), ((s + 3) & 3) * 1024);
                const int cb = (s & 3) * 1024;
#pragma unroll
                for (int ks2 = 0; ks2 < 2; ++ks2) {
                    const int ks = kk * 2 + ks2;
                    unsigned bh[4];
#pragma unroll
                    for (int p = 0; p < 4; ++p)
                        PACKB(hr[8*ks + 2*p], hr[8*ks + 2*p + 1], bh[p]);
                    u32x4 thi = {bh[0], bh[1], bh[2], bh[3]};
                    const short8 Bh = __builtin_bit_cast(short8, thi);
#pragma unroll
                    for (int j = 0; j < 8; ++j) {
                        const short8 Ah = __builtin_bit_cast(short8,
                            wf[cb + ks2*512 + j*64 + lane]);
                        ac[j] = __builtin_amdgcn_mfma_f32_16x16x32_bf16(Ah, Bh, ac[j], 0, 0, 0);
                    }
                }
            }
            // tanh + b1, pack into t (phi-layout)
#pragma unroll
            for (int j = 0; j < 8; ++j) {
                const int mt = pass * 8 + j;
                const float4 bq = *(const float4*)&b1_reg[G * CPAD + mt * 4];
                float tv[4];
#pragma unroll
                for (int r = 0; r < 4; ++r) {
                    float x = ac[j][r] + ((r==0)?bq.x:(r==1)?bq.y:(r==2)?bq.z:bq.w);
                    float e = __expf(2.0f * x);
                    tv[r] = 1.0f - 2.0f * __builtin_amdgcn_rcpf(e + 1.0f);
                }
                const int ti = 4 * (mt >> 1) + 2 * (mt & 1);
                PACKB(tv[0], tv[1], tph[ti]);
                PACKB(tv[2], tv[3], tph[ti + 1]);
            }
        }

        // ---------- G2: h' = (h + b2 + force) + W2 t ----------
        const float csum = 1.0f + c0 + c1 + c2;
#pragma unroll
        for (int pass = 0; pass < 2; ++pass) {
            f32x4 ac[8];
#pragma unroll
            for (int j = 0; j < 8; ++j) {
                const int mt = pass * 8 + j;
                const float4 a0 = *(const float4*)&an_reg[0][G * CPAD + mt * 4];
                const float4 a1 = *(const float4*)&an_reg[1][G * CPAD + mt * 4];
                const float4 a2 = *(const float4*)&an_reg[2][G * CPAD + mt * 4];
                const float4 bq = *(const float4*)&b2_reg[G * CPAD + mt * 4];
                ac[j][0] = hr[mt*4+0]*csum - (c0*a0.x + c1*a1.x + c2*a2.x) + bq.x;
                ac[j][1] = hr[mt*4+1]*csum - (c0*a0.y + c1*a1.y + c2*a2.y) + bq.y;
                ac[j][2] = hr[mt*4+2]*csum - (c0*a0.z + c1*a1.z + c2*a2.z) + bq.z;
                ac[j][3] = hr[mt*4+3]*csum - (c0*a0.w + c1*a1.w + c2*a2.w) + bq.w;
            }
#pragma unroll
            for (int kk = 0; kk < 4; ++kk) {
                const int s = 8 + pass * 4 + kk;
                PIPE_SYNC();
                STAGE(CHB((s + 3) & 15), ((s + 3) & 3) * 1024);
                const int cb = (s & 3) * 1024;
#pragma unroll
                for (int ks2 = 0; ks2 < 2; ++ks2) {
                    const int ks = kk * 2 + ks2;
                    u32x4 thi = {tph[4*ks+0], tph[4*ks+1], tph[4*ks+2], tph[4*ks+3]};
                    const short8 Bh = __builtin_bit_cast(short8, thi);
#pragma unroll
                    for (int j = 0; j < 8; ++j) {
                        const short8 Ah = __builtin_bit_cast(short8,
                            wf[cb + ks2*512 + j*64 + lane]);
                        ac[j] = __builtin_amdgcn_mfma_f32_16x16x32_bf16(Ah, Bh, ac[j], 0, 0, 0);
                    }
                }
            }
#pragma unroll
            for (int j = 0; j < 8; ++j) {
                const int mt = pass * 8 + j;
                hr[mt*4+0] = ac[j][0]; hr[mt*4+1] = ac[j][1];
                hr[mt*4+2] = ac[j][2]; hr[mt*4+3] = ac[j][3];
            }
        }

        // ---------- norm clip (in regs) ----------
        {
            float ss = 0.0f;
#pragma unroll
            for (int s = 0; s < 64; ++s) ss += hr[s] * hr[s];
            ss += __shfl_xor(ss, 16);
            ss += __shfl_xor(ss, 32);
            const float n = sqrtf(ss);
            const float sc = (n > 10.0f) ? (10.0f / (n + 1e-8f)) : 1.0f;
#pragma unroll
            for (int s = 0; s < 64; ++s) hr[s] *= sc;
        }
    }

    // ---------- store h_final ----------
#pragma unroll
    for (int mt = 0; mt < 16; ++mt) {
        float4 v;
        v.x = hr[mt*4+0]; v.y = hr[mt*4+1]; v.z = hr[mt*4+2]; v.w = hr[mt*4+3];
        *(float4*)&out_h[(size_t)bglob * DIMX + 16 * mt + 4 * G] = v;
    }
}

extern "C" void kernel_launch(void* const* d_in, const int* in_sizes, int n_in,
                              void* d_out, int out_size, void* d_ws, size_t ws_size,
                              hipStream_t stream) {
    const float* h0      = (const float*)d_in[0];
    const float* W1      = (const float*)d_in[1];
    const float* b1      = (const float*)d_in[2];
    const float* W2      = (const float*)d_in[3];
    const float* b2      = (const float*)d_in[4];
    const float* anchors = (const float*)d_in[5];
    const int B = in_sizes[0] / DIMX;

    float* out_h     = (float*)d_out;
    float* out_align = out_h + (long long)B * DIMX;
    float* out_div   = out_align + (long long)NL * B * 3;
    float* out_tens  = out_div   + (long long)NL * B * 3;

    u32x4* ws = (u32x4*)d_ws;   // 256 KiB

    hipLaunchKernelGGL(wsplit, dim3(64), dim3(256), 0, stream, W1, W2, ws);
    hipLaunchKernelGGL(collapse_mfma16, dim3(B / 64), dim3(256), 0, stream,
                       h0, b1, b2, anchors, ws,
                       out_h, out_align, out_div, out_tens, B);
}

// Round 14
// 333.139 us; speedup vs baseline: 12.9174x; 2.4314x over previous
//
#include <hip/hip_runtime.h>
#include <math.h>

// CollapseEngine R14: R9 body + force-fold. G2's rank-4 init term
// (-cf0*a0n - cf1*a1n - cf2*a2n + b2) moves into ONE extra MFMA per tile
// using a 4-slot virtual K-step: A_ext = [-a0n;-a1n;-a2n;b2] (const frags,
// 16KB LDS staged once), B_ext = [cf0,cf1,cf2,1] (G==0 lanes). Init becomes
// a single mul (h*csum). Saves ~350 VALU + 64 ds_reads per wave-layer.
// Everything else identical to R9 (545 us champion).
// phi(ks,G,i) = 32*ks + 16*(i>>2) + 4*G + (i&3),  G = lane>>4.

#define DIMX 256
#define NL 6
#define CPAD 68   // padded float stride for per-G const arrays

typedef float f32x4 __attribute__((ext_vector_type(4)));
typedef short short8 __attribute__((ext_vector_type(8)));
typedef unsigned int u32x4 __attribute__((ext_vector_type(4)));

// 16 chunks of 1024 granules (16KB); chunk c = (g*2+pass)*4 + kk, kk=ks>>1
#define CHB(c) ((c) * 1024)
// ext A-frags: granules 16384..17407: [pass(2)][t8(8)][lane(64)]
#define EXTB 16384

// RNE-pack f32 pair -> u32 of 2 bf16 (lo = X0, hi = X1)
#define PACKB(X0, X1, DST)                                                       \
    asm("v_cvt_pk_bf16_f32 %0, %1, %2" : "=v"(DST) : "v"(X0), "v"(X1));

// ---------------- W frag + ext-frag precompute ----------------
__global__ void wsplit(const float* __restrict__ W1, const float* __restrict__ W2,
                       const float* __restrict__ anchors, const float* __restrict__ b2f,
                       u32x4* __restrict__ ws) {
    int gi = blockIdx.x * 256 + threadIdx.x;        // 0..17407
    if (gi < 16384) {
        int ln   = gi & 63;
        int t8   = (gi >> 6) & 7;
        int ks2  = (gi >> 9) & 1;
        int kk   = (gi >> 10) & 3;
        int pass = (gi >> 12) & 1;
        int g    = (gi >> 13) & 1;
        int ks   = kk * 2 + ks2;
        int m    = (pass * 8 + t8) * 16 + (ln & 15);
        int G    = ln >> 4;
        const float* Wg = g ? W2 : W1;
        unsigned o[4];
#pragma unroll
        for (int p = 0; p < 4; ++p) {
            int f = 32 * ks + ((p >> 1) << 4) + 4 * G + ((p & 1) << 1);
            float x0 = Wg[m * DIMX + f];
            float x1 = Wg[m * DIMX + f + 1];
            unsigned hp;
            PACKB(x0, x1, hp);
            o[p] = hp;
        }
        u32x4 out = {o[0], o[1], o[2], o[3]};
        ws[gi] = out;
    } else {
        // ext A-frags: A_ext[m][k]: k=0..2 -> -a_kn[fout], k=3 -> b2[fout], else 0
        int r    = gi - EXTB;
        int pass = r >> 9;
        int t8   = (r >> 6) & 7;
        int ln   = r & 63;
        int m    = ln & 15;
        int G    = ln >> 4;
        int fout = (pass * 8 + t8) * 16 + m;
        float inv[3];
#pragma unroll
        for (int k = 0; k < 3; ++k) {
            float ss = 0.0f;
            for (int f = 0; f < DIMX; ++f) {
                float a = anchors[k * DIMX + f];
                ss += a * a;
            }
            inv[k] = 1.0f / fmaxf(sqrtf(ss), 1e-12f);
        }
        float v[8];
#pragma unroll
        for (int i = 0; i < 8; ++i) {
            int k = G * 8 + i;
            v[i] = (k == 0) ? -anchors[fout] * inv[0]
                 : (k == 1) ? -anchors[DIMX + fout] * inv[1]
                 : (k == 2) ? -anchors[2 * DIMX + fout] * inv[2]
                 : (k == 3) ? b2f[fout] : 0.0f;
        }
        unsigned o[4];
#pragma unroll
        for (int p = 0; p < 4; ++p) {
            unsigned hp;
            PACKB(v[2 * p], v[2 * p + 1], hp);
            o[p] = hp;
        }
        u32x4 out = {o[0], o[1], o[2], o[3]};
        ws[gi] = out;
    }
}

// ---------------- main fused kernel ----------------

// stage one 16KB chunk (1024 granules): 512 thr x 2 x 16B
#define STAGE(gIdxBase, ldsSlotBase)                                             \
    {                                                                            \
        _Pragma("unroll")                                                        \
        for (int i_ = 0; i_ < 2; ++i_) {                                         \
            const int off_ = ((w * 2 + i_) << 6);                                \
            __builtin_amdgcn_global_load_lds(                                    \
                (const __attribute__((address_space(1))) void*)(ws + (gIdxBase) + off_ + lane), \
                (__attribute__((address_space(3))) void*)(&wf[(ldsSlotBase) + off_]),           \
                16, 0, 0);                                                       \
        }                                                                        \
    }

// counted-vmcnt pipeline barrier (unchanged from R9)
#define PIPE_SYNC()                                                              \
    {                                                                            \
        asm volatile("s_waitcnt vmcnt(4)" ::: "memory");                         \
        __builtin_amdgcn_sched_barrier(0);                                       \
        __builtin_amdgcn_s_barrier();                                            \
        __builtin_amdgcn_sched_barrier(0);                                       \
    }

__global__ __launch_bounds__(512, 2)
void collapse_mfma16(const float* __restrict__ h0,
                     const float* __restrict__ b1f,
                     const float* __restrict__ anchors,
                     const u32x4* __restrict__ ws,
                     float* __restrict__ out_h,
                     float* __restrict__ out_align,
                     float* __restrict__ out_div,
                     float* __restrict__ out_tens,
                     int B)
{
    __shared__ __align__(16) u32x4 wf[4096];         // 4 x 16KB W-frag buffers
    __shared__ __align__(16) u32x4 wext[1024];       // 16KB ext A-frags (static)
    __shared__ __align__(16) float an_reg[3][272];   // padded (stride CPAD=68)
    __shared__ __align__(16) float b1_reg[272];
    __shared__ float an_inv[3];

    const int tid  = threadIdx.x;
    const int w    = tid >> 6;
    const int lane = tid & 63;
    const int G    = lane >> 4;          // k-octet / D-row group
    const int c    = lane & 15;          // batch col within wave tile
    const int bglob = blockIdx.x * 128 + w * 16 + c;

    // ext A-frags: stage once, FIRST (oldest loads -> drained by first sync)
    {
#pragma unroll
        for (int i_ = 0; i_ < 2; ++i_) {
            const int off_ = ((w * 2 + i_) << 6);
            __builtin_amdgcn_global_load_lds(
                (const __attribute__((address_space(1))) void*)(ws + EXTB + off_ + lane),
                (__attribute__((address_space(3))) void*)(&wext[off_]),
                16, 0, 0);
        }
    }

    // anchor inverse norms (waves 0..2)
    if (w < 3) {
        const float4 av = *(const float4*)&anchors[w * DIMX + lane * 4];
        float ss = av.x * av.x + av.y * av.y + av.z * av.z + av.w * av.w;
#pragma unroll
        for (int m = 1; m < 64; m <<= 1) ss += __shfl_xor(ss, m, 64);
        if (lane == 0) an_inv[w] = 1.0f / fmaxf(sqrtf(ss), 1e-12f);
    }
    __syncthreads();

    // const arrays in phi-layout, padded: idx = Gc*CPAD + s,
    // feat f = 16*(s>>2) + 4*Gc + (s&3)
    {
        int idx = tid & 255;
        int Gc = idx >> 6, s = idx & 63;
        int f = 16 * (s >> 2) + 4 * Gc + (s & 3);
        int pidx = Gc * CPAD + s;
        if (tid < 256) {
            b1_reg[pidx] = b1f[f];
        } else {
#pragma unroll
            for (int k = 0; k < 3; ++k)
                an_reg[k][pidx] = anchors[k * DIMX + f] * an_inv[k];
        }
    }
    __syncthreads();

    // load h0 into phi-layout regs: hr[mt*4+r] = h0[row][16mt+4G+r]
    float hr[64];
#pragma unroll
    for (int mt = 0; mt < 16; ++mt) {
        const float4 v = *(const float4*)&h0[(size_t)bglob * DIMX + 16 * mt + 4 * G];
        hr[mt * 4 + 0] = v.x; hr[mt * 4 + 1] = v.y;
        hr[mt * 4 + 2] = v.z; hr[mt * 4 + 3] = v.w;
    }

    // pipeline prologue: prefetch chunks 0,1,2 into bufs 0,1,2
    STAGE(CHB(0), 0);
    STAGE(CHB(1), 1024);
    STAGE(CHB(2), 2048);

#pragma unroll 1
    for (int layer = 0; layer < NL; ++layer) {
        // ---------- stats: p0=|h|^2, dk=h.Ak ; |h-Ak|^2 = p0-2dk+1 ----------
        float p0 = 0, d0 = 0, d1 = 0, d2 = 0;
#pragma unroll
        for (int q = 0; q < 16; ++q) {
            const float4 a0 = *(const float4*)&an_reg[0][G * CPAD + q * 4];
            const float4 a1 = *(const float4*)&an_reg[1][G * CPAD + q * 4];
            const float4 a2 = *(const float4*)&an_reg[2][G * CPAD + q * 4];
            float x;
            x = hr[q*4+0]; p0 += x*x; d0 += x*a0.x; d1 += x*a1.x; d2 += x*a2.x;
            x = hr[q*4+1]; p0 += x*x; d0 += x*a0.y; d1 += x*a1.y; d2 += x*a2.y;
            x = hr[q*4+2]; p0 += x*x; d0 += x*a0.z; d1 += x*a1.z; d2 += x*a2.z;
            x = hr[q*4+3]; p0 += x*x; d0 += x*a0.w; d1 += x*a1.w; d2 += x*a2.w;
        }
        p0 += __shfl_xor(p0, 16); d0 += __shfl_xor(d0, 16);
        d1 += __shfl_xor(d1, 16); d2 += __shfl_xor(d2, 16);
        p0 += __shfl_xor(p0, 32); d0 += __shfl_xor(d0, 32);
        d1 += __shfl_xor(d1, 32); d2 += __shfl_xor(d2, 32);
        const float inv_rn = 1.0f / fmaxf(sqrtf(p0), 1e-12f);
        const float al0 = d0 * inv_rn, al1 = d1 * inv_rn, al2 = d2 * inv_rn;
        const float dv0 = 1.0f - al0, dv1 = 1.0f - al1, dv2 = 1.0f - al2;
        const float c0 = -0.10f * dv0 / fmaxf(sqrtf(fmaxf(p0 - 2.0f*d0 + 1.0f, 0.0f)), 1e-12f);
        const float c1 = -0.10f * dv1 / fmaxf(sqrtf(fmaxf(p0 - 2.0f*d1 + 1.0f, 0.0f)), 1e-12f);
        const float c2 = -0.05f * dv2 / fmaxf(sqrtf(fmaxf(p0 - 2.0f*d2 + 1.0f, 0.0f)), 1e-12f);
        if (G == 0) {
            const long long tb = ((long long)layer * B + bglob) * 3;
            out_align[tb+0] = al0; out_align[tb+1] = al1; out_align[tb+2] = al2;
            out_div[tb+0] = dv0;   out_div[tb+1] = dv1;   out_div[tb+2] = dv2;
            out_tens[tb+0] = dv0*dv0; out_tens[tb+1] = dv1*dv1; out_tens[tb+2] = dv2*dv2;
        }
        // B_ext = [cf0, cf1, cf2, 1] on G==0 lanes (virtual K-slots 0..3)
        unsigned be0 = 0, be1 = 0;
        if (G == 0) {
            PACKB(c0, c1, be0);
            PACKB(c2, 1.0f, be1);
        }
        u32x4 bev = {be0, be1, 0u, 0u};
        const short8 Bext = __builtin_bit_cast(short8, bev);

        // ---------- G1: t = tanh(W1 h + b1); windows = (pass, kk) ----------
        unsigned tph[32];
#pragma unroll
        for (int pass = 0; pass < 2; ++pass) {
            f32x4 ac[8];
#pragma unroll
            for (int j = 0; j < 8; ++j) ac[j] = (f32x4)(0.0f);
#pragma unroll
            for (int kk = 0; kk < 4; ++kk) {
                const int s = pass * 4 + kk;
                PIPE_SYNC();
                STAGE(CHB((s + 3) & 15), ((s + 3) & 3) * 1024);
                const int cb = (s & 3) * 1024;
#pragma unroll
                for (int ks2 = 0; ks2 < 2; ++ks2) {
                    const int ks = kk * 2 + ks2;
                    unsigned bh[4];
#pragma unroll
                    for (int p = 0; p < 4; ++p)
                        PACKB(hr[8*ks + 2*p], hr[8*ks + 2*p + 1], bh[p]);
                    u32x4 thi = {bh[0], bh[1], bh[2], bh[3]};
                    const short8 Bh = __builtin_bit_cast(short8, thi);
#pragma unroll
                    for (int j = 0; j < 8; ++j) {
                        const short8 Ah = __builtin_bit_cast(short8,
                            wf[cb + ks2*512 + j*64 + lane]);
                        ac[j] = __builtin_amdgcn_mfma_f32_16x16x32_bf16(Ah, Bh, ac[j], 0, 0, 0);
                    }
                }
            }
            // tanh + b1, pack into t (phi-layout)
#pragma unroll
            for (int j = 0; j < 8; ++j) {
                const int mt = pass * 8 + j;
                const float4 bq = *(const float4*)&b1_reg[G * CPAD + mt * 4];
                float tv[4];
#pragma unroll
                for (int r = 0; r < 4; ++r) {
                    float x = ac[j][r] + ((r==0)?bq.x:(r==1)?bq.y:(r==2)?bq.z:bq.w);
                    float e = __expf(2.0f * x);
                    tv[r] = 1.0f - 2.0f * __builtin_amdgcn_rcpf(e + 1.0f);
                }
                const int ti = 4 * (mt >> 1) + 2 * (mt & 1);
                PACKB(tv[0], tv[1], tph[ti]);
                PACKB(tv[2], tv[3], tph[ti + 1]);
            }
        }

        // ---------- G2: h' = csum*h [+ext MFMA: -Σcf*a + b2] + W2 t ----------
        const float csum = 1.0f + c0 + c1 + c2;
#pragma unroll
        for (int pass = 0; pass < 2; ++pass) {
            f32x4 ac[8];
#pragma unroll
            for (int j = 0; j < 8; ++j) {
                const int mt = pass * 8 + j;
                ac[j][0] = hr[mt*4+0]*csum;
                ac[j][1] = hr[mt*4+1]*csum;
                ac[j][2] = hr[mt*4+2]*csum;
                ac[j][3] = hr[mt*4+3]*csum;
            }
            // rank-4 fold: ac[j] += A_ext @ B_ext
#pragma unroll
            for (int j = 0; j < 8; ++j) {
                const short8 Ax = __builtin_bit_cast(short8, wext[pass*512 + j*64 + lane]);
                ac[j] = __builtin_amdgcn_mfma_f32_16x16x32_bf16(Ax, Bext, ac[j], 0, 0, 0);
            }
#pragma unroll
            for (int kk = 0; kk < 4; ++kk) {
                const int s = 8 + pass * 4 + kk;
                PIPE_SYNC();
                STAGE(CHB((s + 3) & 15), ((s + 3) & 3) * 1024);
                const int cb = (s & 3) * 1024;
#pragma unroll
                for (int ks2 = 0; ks2 < 2; ++ks2) {
                    const int ks = kk * 2 + ks2;
                    u32x4 thi = {tph[4*ks+0], tph[4*ks+1], tph[4*ks+2], tph[4*ks+3]};
                    const short8 Bh = __builtin_bit_cast(short8, thi);
#pragma unroll
                    for (int j = 0; j < 8; ++j) {
                        const short8 Ah = __builtin_bit_cast(short8,
                            wf[cb + ks2*512 + j*64 + lane]);
                        ac[j] = __builtin_amdgcn_mfma_f32_16x16x32_bf16(Ah, Bh, ac[j], 0, 0, 0);
                    }
                }
            }
#pragma unroll
            for (int j = 0; j < 8; ++j) {
                const int mt = pass * 8 + j;
                hr[mt*4+0] = ac[j][0]; hr[mt*4+1] = ac[j][1];
                hr[mt*4+2] = ac[j][2]; hr[mt*4+3] = ac[j][3];
            }
        }

        // ---------- norm clip (in regs) ----------
        {
            float ss = 0.0f;
#pragma unroll
            for (int s = 0; s < 64; ++s) ss += hr[s] * hr[s];
            ss += __shfl_xor(ss, 16);
            ss += __shfl_xor(ss, 32);
            const float n = sqrtf(ss);
            const float sc = (n > 10.0f) ? (10.0f / (n + 1e-8f)) : 1.0f;
#pragma unroll
            for (int s = 0; s < 64; ++s) hr[s] *= sc;
        }
    }

    // ---------- store h_final ----------
#pragma unroll
    for (int mt = 0; mt < 16; ++mt) {
        float4 v;
        v.x = hr[mt*4+0]; v.y = hr[mt*4+1]; v.z = hr[mt*4+2]; v.w = hr[mt*4+3];
        *(float4*)&out_h[(size_t)bglob * DIMX + 16 * mt + 4 * G] = v;
    }
}

extern "C" void kernel_launch(void* const* d_in, const int* in_sizes, int n_in,
                              void* d_out, int out_size, void* d_ws, size_t ws_size,
                              hipStream_t stream) {
    const float* h0      = (const float*)d_in[0];
    const float* W1      = (const float*)d_in[1];
    const float* b1      = (const float*)d_in[2];
    const float* W2      = (const float*)d_in[3];
    const float* b2      = (const float*)d_in[4];
    const float* anchors = (const float*)d_in[5];
    const int B = in_sizes[0] / DIMX;

    float* out_h     = (float*)d_out;
    float* out_align = out_h + (long long)B * DIMX;
    float* out_div   = out_align + (long long)NL * B * 3;
    float* out_tens  = out_div   + (long long)NL * B * 3;

    u32x4* ws = (u32x4*)d_ws;   // 272 KiB (16384 W-frag + 1024 ext granules)

    hipLaunchKernelGGL(wsplit, dim3(68), dim3(256), 0, stream, W1, W2, anchors, b2, ws);
    hipLaunchKernelGGL(collapse_mfma16, dim3(B / 128), dim3(512), 0, stream,
                       h0, b1, anchors, ws,
                       out_h, out_align, out_div, out_tens, B);
}